// Round 1
// baseline (410.886 us; speedup 1.0000x reference)
//
#include <hip/hip_runtime.h>
#include <hip/hip_bf16.h>

typedef unsigned int u32;
typedef unsigned short u16;
typedef __bf16 bf16x8 __attribute__((ext_vector_type(8)));
typedef float f32x4 __attribute__((ext_vector_type(4)));

#define B_ 4
#define T_ 2048
#define C_ 1024
#define H_ 16
#define HD_ 64
#define M_ (B_*T_)
#define N3C (3*C_)

__device__ __forceinline__ u16 f2bf(float f) {
  u32 u = __builtin_bit_cast(u32, f);
  u = (u + 0x7fffu + ((u >> 16) & 1u)) >> 16;
  return (u16)u;
}

#define GLD16(gp, lp) __builtin_amdgcn_global_load_lds( \
    (const __attribute__((address_space(1))) u32*)(gp), \
    (__attribute__((address_space(3))) u32*)(lp), 16, 0, 0)

#if __has_builtin(__builtin_amdgcn_exp2f)
#define EXP2F(x) __builtin_amdgcn_exp2f(x)
#else
#define EXP2F(x) exp2f(x)
#endif

// ---------------- fp32 -> bf16 bulk convert ----------------
__global__ __launch_bounds__(256) void cvt_f32_to_bf16(
    const float* __restrict__ in, u16* __restrict__ out, int n4) {
  int i = blockIdx.x * blockDim.x + threadIdx.x;
  if (i < n4) {
    float4 v = ((const float4*)in)[i];
    ushort4 o;
    o.x = f2bf(v.x); o.y = f2bf(v.y); o.z = f2bf(v.z); o.w = f2bf(v.w);
    ((ushort4*)out)[i] = o;
  }
}

// ---------------- W [K][N] fp32 -> Wt [N][K] bf16 ----------------
__global__ __launch_bounds__(256) void transpose_cvt(
    const float* __restrict__ W, u16* __restrict__ Wt, int Kdim, int Ndim) {
  __shared__ float t[32][33];
  int n0 = blockIdx.x * 32, k0 = blockIdx.y * 32;
  int tx = threadIdx.x, ty = threadIdx.y;
  #pragma unroll
  for (int i = ty; i < 32; i += 8)
    t[i][tx] = W[(long)(k0 + i) * Ndim + n0 + tx];
  __syncthreads();
  #pragma unroll
  for (int i = ty; i < 32; i += 8)
    Wt[(long)(n0 + i) * Kdim + k0 + tx] = f2bf(t[tx][i]);
}

// ---------------- v-part of qkv -> vt[bh][hd][T] ----------------
__global__ __launch_bounds__(256) void transpose_v(
    const u16* __restrict__ qkv, u16* __restrict__ vt) {
  const int t0 = blockIdx.x * 64, bh = blockIdx.y;
  const int b = bh >> 4, h = bh & 15;
  #pragma unroll
  for (int i = 0; i < 16; ++i) {
    int idx = threadIdx.x + i * 256;
    int d = idx >> 6, t = idx & 63;
    vt[((long)bh * HD_ + d) * T_ + t0 + t] =
        qkv[(long)(b * T_ + t0 + t) * N3C + 2 * C_ + h * HD_ + d];
  }
}

// ---------------- GEMM: C[M][N] = A[M][K] * Bt[N][K]^T + bias ----------------
// 128x128 tile, BK=64, 4 waves each 64x64 (4x4 of 16x16x32 MFMA).
// LDS staged via global_load_lds(16B) with XOR chunk swizzle: 16B chunk c of
// row r lives at slot c ^ (r&7)  -> staging stays lane-contiguous, fragment
// ds_read_b128 is 2-way-conflict-free.
template<int WRITE_BF16>
__global__ __launch_bounds__(256) void gemm_bt(
    const u16* __restrict__ A, const u16* __restrict__ Bt,
    const float* __restrict__ bias, void* __restrict__ Cout,
    int N, int K) {
  __shared__ u16 As[128 * 64];
  __shared__ u16 Bs[128 * 64];
  const int tid = threadIdx.x;
  const int wave = tid >> 6, lane = tid & 63;
  const int wm = wave >> 1, wn = wave & 1;
  const int l15 = lane & 15, quad = lane >> 4;
  const int rA = lane >> 3, cxor = (lane & 7) ^ rA;
  const long rowA0 = (long)blockIdx.x * 128;
  const long colB0 = (long)blockIdx.y * 128;

  f32x4 acc[4][4] = {};

  const u16* Ag = A + (rowA0 + wave * 32 + rA) * K + cxor * 8;
  const u16* Bg = Bt + (colB0 + wave * 32 + rA) * K + cxor * 8;
  u16* Asw = &As[(wave * 32) * 64];
  u16* Bsw = &Bs[(wave * 32) * 64];

  for (int k0 = 0; k0 < K; k0 += 64) {
    #pragma unroll
    for (int j = 0; j < 4; ++j) {
      GLD16(Ag + (long)j * 8 * K + k0, Asw + j * 8 * 64);
      GLD16(Bg + (long)j * 8 * K + k0, Bsw + j * 8 * 64);
    }
    __syncthreads();
    #pragma unroll
    for (int kk = 0; kk < 2; ++kk) {
      bf16x8 af[4], bfr[4];
      #pragma unroll
      for (int mt = 0; mt < 4; ++mt) {
        int r = wm * 64 + mt * 16 + l15;
        int c = (kk * 4 + quad) ^ (r & 7);
        af[mt] = *(const bf16x8*)&As[r * 64 + c * 8];
      }
      #pragma unroll
      for (int nt = 0; nt < 4; ++nt) {
        int r = wn * 64 + nt * 16 + l15;
        int c = (kk * 4 + quad) ^ (r & 7);
        bfr[nt] = *(const bf16x8*)&Bs[r * 64 + c * 8];
      }
      #pragma unroll
      for (int mt = 0; mt < 4; ++mt)
        #pragma unroll
        for (int nt = 0; nt < 4; ++nt)
          acc[mt][nt] = __builtin_amdgcn_mfma_f32_16x16x32_bf16(
              af[mt], bfr[nt], acc[mt][nt], 0, 0, 0);
    }
    __syncthreads();
  }

  float bl[4];
  #pragma unroll
  for (int nt = 0; nt < 4; ++nt)
    bl[nt] = bias[colB0 + wn * 64 + nt * 16 + l15];
  #pragma unroll
  for (int mt = 0; mt < 4; ++mt) {
    long row = rowA0 + wm * 64 + mt * 16 + quad * 4;
    #pragma unroll
    for (int nt = 0; nt < 4; ++nt) {
      long col = colB0 + wn * 64 + nt * 16 + l15;
      #pragma unroll
      for (int r = 0; r < 4; ++r) {
        float v = acc[mt][nt][r] + bl[nt];
        if (WRITE_BF16) ((u16*)Cout)[(row + r) * N + col] = f2bf(v);
        else            ((float*)Cout)[(row + r) * N + col] = v;
      }
    }
  }
}

// ---------------- flash attention ----------------
// Block: 64 q-rows (4 waves x 16), loops over 64-wide k-tiles up to diagonal.
// Q frags in regs; K-tile + Vt-tile staged via swizzled global_load_lds;
// P converted C/D layout -> A layout via per-wave padded LDS buffer.
__global__ __launch_bounds__(256) void flash_attn(
    const u16* __restrict__ qkv, const u16* __restrict__ vt,
    u16* __restrict__ yb) {
  __shared__ u16 Ks[64 * 64];
  __shared__ u16 Vts[64 * 64];
  __shared__ u16 Ps[4][16 * 72];
  const int qt = (int)gridDim.x - 1 - (int)blockIdx.x;  // longest blocks first
  const int bh = blockIdx.y;
  const int b = bh >> 4, h = bh & 15;
  const int tid = threadIdx.x, wave = tid >> 6, lane = tid & 63;
  const int l15 = lane & 15, quad = lane >> 4;
  const int rA = lane >> 3, cxor = (lane & 7) ^ rA;

  const u16* Qb = qkv + (long)b * T_ * N3C + h * HD_;
  const u16* Kb = Qb + C_;
  const u16* Vb = vt + (long)bh * HD_ * T_;

  const int qrow = qt * 64 + wave * 16 + l15;
  bf16x8 aq0 = *(const bf16x8*)&Qb[(long)qrow * N3C + quad * 8];
  bf16x8 aq1 = *(const bf16x8*)&Qb[(long)qrow * N3C + 32 + quad * 8];

  float m_i[4], l_i[4];
  f32x4 o[4] = {};
  #pragma unroll
  for (int r = 0; r < 4; ++r) { m_i[r] = -__builtin_inff(); l_i[r] = 0.f; }

  const float cs = 0.125f * 1.44269504088896340736f;  // 1/sqrt(64) * log2(e)

  const int nKT = qt + 1;
  for (int kt = 0; kt < nKT; ++kt) {
    #pragma unroll
    for (int j = 0; j < 2; ++j) {
      int r = wave * 16 + j * 8;
      GLD16(&Kb[(long)(kt * 64 + r + rA) * N3C + cxor * 8], &Ks[r * 64]);
      GLD16(&Vb[(long)(r + rA) * T_ + kt * 64 + cxor * 8], &Vts[r * 64]);
    }
    __syncthreads();

    f32x4 S[4] = {};
    #pragma unroll
    for (int kk = 0; kk < 2; ++kk) {
      bf16x8 a = kk ? aq1 : aq0;
      #pragma unroll
      for (int nt = 0; nt < 4; ++nt) {
        int r = nt * 16 + l15;
        int c = (kk * 4 + quad) ^ (r & 7);
        bf16x8 bk = *(const bf16x8*)&Ks[r * 64 + c * 8];
        S[nt] = __builtin_amdgcn_mfma_f32_16x16x32_bf16(a, bk, S[nt], 0, 0, 0);
      }
    }
    #pragma unroll
    for (int nt = 0; nt < 4; ++nt) S[nt] *= cs;

    if (kt == qt) {  // diagonal tile: causal mask
      #pragma unroll
      for (int nt = 0; nt < 4; ++nt)
        #pragma unroll
        for (int r = 0; r < 4; ++r)
          if (nt * 16 + l15 > wave * 16 + quad * 4 + r)
            S[nt][r] = -__builtin_inff();
    }

    float mx[4];
    #pragma unroll
    for (int r = 0; r < 4; ++r)
      mx[r] = fmaxf(fmaxf(S[0][r], S[1][r]), fmaxf(S[2][r], S[3][r]));
    #pragma unroll
    for (int off = 1; off < 16; off <<= 1)
      #pragma unroll
      for (int r = 0; r < 4; ++r)
        mx[r] = fmaxf(mx[r], __shfl_xor(mx[r], off));

    float al[4];
    #pragma unroll
    for (int r = 0; r < 4; ++r) {
      float nm = fmaxf(m_i[r], mx[r]);
      al[r] = EXP2F(m_i[r] - nm);
      m_i[r] = nm;
    }
    f32x4 P[4];
    #pragma unroll
    for (int nt = 0; nt < 4; ++nt)
      #pragma unroll
      for (int r = 0; r < 4; ++r)
        P[nt][r] = EXP2F(S[nt][r] - m_i[r]);
    float rs[4];
    #pragma unroll
    for (int r = 0; r < 4; ++r) rs[r] = (P[0][r] + P[1][r]) + (P[2][r] + P[3][r]);
    #pragma unroll
    for (int off = 1; off < 16; off <<= 1)
      #pragma unroll
      for (int r = 0; r < 4; ++r) rs[r] += __shfl_xor(rs[r], off);
    #pragma unroll
    for (int r = 0; r < 4; ++r) l_i[r] = l_i[r] * al[r] + rs[r];
    #pragma unroll
    for (int nt = 0; nt < 4; ++nt)
      #pragma unroll
      for (int r = 0; r < 4; ++r) o[nt][r] *= al[r];

    // P: C/D layout -> LDS -> A layout (per-wave buffer, padded stride 72)
    u16* Pw = (u16*)Ps[wave];
    #pragma unroll
    for (int nt = 0; nt < 4; ++nt)
      #pragma unroll
      for (int r = 0; r < 4; ++r)
        Pw[(quad * 4 + r) * 72 + nt * 16 + l15] = f2bf(P[nt][r]);

    bf16x8 ap0 = *(const bf16x8*)&Pw[l15 * 72 + quad * 8];
    bf16x8 ap1 = *(const bf16x8*)&Pw[l15 * 72 + 32 + quad * 8];
    #pragma unroll
    for (int kk = 0; kk < 2; ++kk) {
      bf16x8 a = kk ? ap1 : ap0;
      #pragma unroll
      for (int nt = 0; nt < 4; ++nt) {
        int r = nt * 16 + l15;
        int c = (kk * 4 + quad) ^ (r & 7);
        bf16x8 bv = *(const bf16x8*)&Vts[r * 64 + c * 8];
        o[nt] = __builtin_amdgcn_mfma_f32_16x16x32_bf16(a, bv, o[nt], 0, 0, 0);
      }
    }
    __syncthreads();
  }

  float inv[4];
  #pragma unroll
  for (int r = 0; r < 4; ++r) inv[r] = 1.f / l_i[r];
  #pragma unroll
  for (int nt = 0; nt < 4; ++nt)
    #pragma unroll
    for (int r = 0; r < 4; ++r) {
      long row = (long)b * T_ + qt * 64 + wave * 16 + quad * 4 + r;
      yb[row * C_ + h * HD_ + nt * 16 + l15] = f2bf(o[nt][r] * inv[r]);
    }
}

extern "C" void kernel_launch(void* const* d_in, const int* in_sizes, int n_in,
                              void* d_out, int out_size, void* d_ws, size_t ws_size,
                              hipStream_t stream) {
  const float* x      = (const float*)d_in[0];
  const float* W_attn = (const float*)d_in[1];
  const float* b_attn = (const float*)d_in[2];
  const float* W_proj = (const float*)d_in[3];
  const float* b_proj = (const float*)d_in[4];
  float* out = (float*)d_out;

  char* ws = (char*)d_ws;
  // layout (bytes):
  //   xb / vt (aliased, vt written only after gemm1 consumed xb): 16.78 MB
  u16* xb   = (u16*)(ws);                      // 8192*1024*2  = 16777216
  u16* vtb  = (u16*)(ws);                      // alias of xb region
  u16* W1t  = (u16*)(ws + 16777216);           // 3072*1024*2  =  6291456
  u16* W2t  = (u16*)(ws + 23068672);           // 1024*1024*2  =  2097152
  u16* qkvb = (u16*)(ws + 25165824);           // 8192*3072*2  = 50331648
  u16* yb   = (u16*)(ws + 75497472);           // 8192*1024*2  = 16777216
  // total: 92274688 bytes

  cvt_f32_to_bf16<<<dim3((M_ * C_ / 4 + 255) / 256), dim3(256), 0, stream>>>(
      x, xb, M_ * C_ / 4);
  transpose_cvt<<<dim3(N3C / 32, C_ / 32), dim3(32, 8), 0, stream>>>(
      W_attn, W1t, C_, N3C);
  transpose_cvt<<<dim3(C_ / 32, C_ / 32), dim3(32, 8), 0, stream>>>(
      W_proj, W2t, C_, C_);
  gemm_bt<1><<<dim3(M_ / 128, N3C / 128), dim3(256), 0, stream>>>(
      xb, W1t, b_attn, qkvb, N3C, C_);
  transpose_v<<<dim3(T_ / 64, B_ * H_), dim3(256), 0, stream>>>(qkvb, vtb);
  flash_attn<<<dim3(T_ / 64, B_ * H_), dim3(256), 0, stream>>>(qkvb, vtb, yb);
  gemm_bt<0><<<dim3(M_ / 128, C_ / 128), dim3(256), 0, stream>>>(
      yb, W2t, b_proj, out, C_, C_);
}

// Round 3
// 319.682 us; speedup vs baseline: 1.2853x; 1.2853x over previous
//
#include <hip/hip_runtime.h>
#include <hip/hip_bf16.h>

typedef unsigned int u32;
typedef unsigned short u16;
typedef __bf16 bf16x8 __attribute__((ext_vector_type(8)));
typedef float f32x4 __attribute__((ext_vector_type(4)));
typedef _Float16 f16;
typedef _Float16 f16x2 __attribute__((ext_vector_type(2)));
typedef _Float16 f16x4 __attribute__((ext_vector_type(4)));

#define B_ 4
#define T_ 2048
#define C_ 1024
#define H_ 16
#define HD_ 64
#define M_ (B_*T_)
#define N3C (3*C_)

__device__ __forceinline__ u16 f2bf(float f) {
  u32 u = __builtin_bit_cast(u32, f);
  u = (u + 0x7fffu + ((u >> 16) & 1u)) >> 16;
  return (u16)u;
}

#define GLD16(gp, lp) __builtin_amdgcn_global_load_lds( \
    (const __attribute__((address_space(1))) u32*)(gp), \
    (__attribute__((address_space(3))) u32*)(lp), 16, 0, 0)

#if __has_builtin(__builtin_amdgcn_exp2f)
#define EXP2F(x) __builtin_amdgcn_exp2f(x)
#else
#define EXP2F(x) exp2f(x)
#endif

// ---------------- fp32 -> bf16 bulk convert ----------------
__global__ __launch_bounds__(256) void cvt_f32_to_bf16(
    const float* __restrict__ in, u16* __restrict__ out, int n4) {
  int i = blockIdx.x * blockDim.x + threadIdx.x;
  if (i < n4) {
    float4 v = ((const float4*)in)[i];
    ushort4 o;
    o.x = f2bf(v.x); o.y = f2bf(v.y); o.z = f2bf(v.z); o.w = f2bf(v.w);
    ((ushort4*)out)[i] = o;
  }
}

// ---------------- W [K][N] fp32 -> Wt [N][K] bf16 ----------------
__global__ __launch_bounds__(256) void transpose_cvt(
    const float* __restrict__ W, u16* __restrict__ Wt, int Kdim, int Ndim) {
  __shared__ float t[32][33];
  int n0 = blockIdx.x * 32, k0 = blockIdx.y * 32;
  int tx = threadIdx.x, ty = threadIdx.y;
  #pragma unroll
  for (int i = ty; i < 32; i += 8)
    t[i][tx] = W[(long)(k0 + i) * Ndim + n0 + tx];
  __syncthreads();
  #pragma unroll
  for (int i = ty; i < 32; i += 8)
    Wt[(long)(n0 + i) * Kdim + k0 + tx] = f2bf(t[tx][i]);
}

// ---------------- v-part of qkv (bf16) -> vt[bh][hd][T] (f16) ----------------
__global__ __launch_bounds__(256) void transpose_v(
    const u16* __restrict__ qkv, f16* __restrict__ vt) {
  const int t0 = blockIdx.x * 64, bh = blockIdx.y;
  const int b = bh >> 4, h = bh & 15;
  const int t = threadIdx.x & 63, dq = threadIdx.x >> 6;  // dq 0..3
  #pragma unroll
  for (int p = 0; p < 4; ++p) {
    int d0 = (p * 4 + dq) * 4;
    ushort4 v = *(const ushort4*)&qkv[
        ((long)(b * T_ + t0 + t)) * N3C + 2 * C_ + h * 64 + d0];
    const u16* vp = (const u16*)&v;
    #pragma unroll
    for (int j = 0; j < 4; ++j) {
      float f = __builtin_bit_cast(float, ((u32)vp[j]) << 16);
      vt[((long)bh * 64 + d0 + j) * T_ + t0 + t] = (f16)f;
    }
  }
}

// ---------------- GEMM: C[M][N] = A[M][K] * Bt[N][K]^T + bias ----------------
template<int WRITE_BF16>
__global__ __launch_bounds__(256) void gemm_bt(
    const u16* __restrict__ A, const u16* __restrict__ Bt,
    const float* __restrict__ bias, void* __restrict__ Cout,
    int N, int K) {
  __shared__ u16 As[128 * 64];
  __shared__ u16 Bs[128 * 64];
  const int tid = threadIdx.x;
  const int wave = tid >> 6, lane = tid & 63;
  const int wm = wave >> 1, wn = wave & 1;
  const int l15 = lane & 15, quad = lane >> 4;
  const int rA = lane >> 3, cxor = (lane & 7) ^ rA;
  const long rowA0 = (long)blockIdx.x * 128;
  const long colB0 = (long)blockIdx.y * 128;

  f32x4 acc[4][4] = {};

  const u16* Ag = A + (rowA0 + wave * 32 + rA) * K + cxor * 8;
  const u16* Bg = Bt + (colB0 + wave * 32 + rA) * K + cxor * 8;
  u16* Asw = &As[(wave * 32) * 64];
  u16* Bsw = &Bs[(wave * 32) * 64];

  for (int k0 = 0; k0 < K; k0 += 64) {
    #pragma unroll
    for (int j = 0; j < 4; ++j) {
      GLD16(Ag + (long)j * 8 * K + k0, Asw + j * 8 * 64);
      GLD16(Bg + (long)j * 8 * K + k0, Bsw + j * 8 * 64);
    }
    __syncthreads();
    #pragma unroll
    for (int kk = 0; kk < 2; ++kk) {
      bf16x8 af[4], bfr[4];
      #pragma unroll
      for (int mt = 0; mt < 4; ++mt) {
        int r = wm * 64 + mt * 16 + l15;
        int c = (kk * 4 + quad) ^ (r & 7);
        af[mt] = *(const bf16x8*)&As[r * 64 + c * 8];
      }
      #pragma unroll
      for (int nt = 0; nt < 4; ++nt) {
        int r = wn * 64 + nt * 16 + l15;
        int c = (kk * 4 + quad) ^ (r & 7);
        bfr[nt] = *(const bf16x8*)&Bs[r * 64 + c * 8];
      }
      #pragma unroll
      for (int mt = 0; mt < 4; ++mt)
        #pragma unroll
        for (int nt = 0; nt < 4; ++nt)
          acc[mt][nt] = __builtin_amdgcn_mfma_f32_16x16x32_bf16(
              af[mt], bfr[nt], acc[mt][nt], 0, 0, 0);
    }
    __syncthreads();
  }

  float bl[4];
  #pragma unroll
  for (int nt = 0; nt < 4; ++nt)
    bl[nt] = bias[colB0 + wn * 64 + nt * 16 + l15];
  #pragma unroll
  for (int mt = 0; mt < 4; ++mt) {
    long row = rowA0 + wm * 64 + mt * 16 + quad * 4;
    #pragma unroll
    for (int nt = 0; nt < 4; ++nt) {
      long col = colB0 + wn * 64 + nt * 16 + l15;
      #pragma unroll
      for (int r = 0; r < 4; ++r) {
        float v = acc[mt][nt][r] + bl[nt];
        if (WRITE_BF16) ((u16*)Cout)[(row + r) * N + col] = f2bf(v);
        else            ((float*)Cout)[(row + r) * N + col] = v;
      }
    }
  }
}

// ---------------- flash attention v2 ----------------
// S^T = K.Q^T (so P^T's C/D regs ARE the 16x16x16 B-frag: no LDS round-trip),
// O^T = V^T.P^T accumulated per q=lane&15 (softmax state per-lane, no shfl fixup).
// K staged via swizzled GLD16 double-buffer; V staged via reg prefetch into
// +8-padded LDS (min-phase reads). One barrier per k-tile.
__global__ __launch_bounds__(256) void flash_attn(
    const u16* __restrict__ qkv, const f16* __restrict__ vt,
    u16* __restrict__ yb) {
  __shared__ u16 Ks[2][64 * 64];
  __shared__ f16 Vts[2][64 * 72];
  const int qt = (int)gridDim.x - 1 - (int)blockIdx.x;  // longest first
  const int bh = blockIdx.y;
  const int b = bh >> 4, h = bh & 15;
  const int tid = threadIdx.x, wave = tid >> 6, lane = tid & 63;
  const int l15 = lane & 15, quad = lane >> 4;
  const int rA = lane >> 3, cxor = (lane & 7) ^ rA;

  const u16* Qb = qkv + (long)b * T_ * N3C + h * HD_;
  const u16* Kb = Qb + C_;
  const f16* Vb = vt + (long)bh * HD_ * T_;

  const int qrow = qt * 64 + wave * 16 + l15;
  const bf16x8 bq0 = *(const bf16x8*)&Qb[(long)qrow * N3C + quad * 8];
  const bf16x8 bq1 = *(const bf16x8*)&Qb[(long)qrow * N3C + 32 + quad * 8];

  const int rv = tid >> 3;   // 0..31 (d-row; +32 for second half)
  const int c16 = tid & 7;   // 16B chunk within 128B row
  const int nKT = qt + 1;

  // preload tile 0
  #pragma unroll
  for (int j = 0; j < 2; ++j) {
    int r = wave * 16 + j * 8;
    GLD16(&Kb[(long)(r + rA) * N3C + cxor * 8], &Ks[0][r * 64]);
  }
  {
    uint4 v0 = *(const uint4*)&Vb[(long)rv * T_ + c16 * 8];
    uint4 v1 = *(const uint4*)&Vb[(long)(rv + 32) * T_ + c16 * 8];
    *(uint4*)&Vts[0][rv * 72 + c16 * 8] = v0;
    *(uint4*)&Vts[0][(rv + 32) * 72 + c16 * 8] = v1;
  }
  __syncthreads();

  const float cs = 0.125f * 1.44269504088896340736f;  // 1/sqrt(HD) * log2(e)
  float ms = -__builtin_inff(), li = 0.f;
  f32x4 o[4] = {};

  for (int kt = 0; kt < nKT; ++kt) {
    const int buf = kt & 1;
    const bool more = (kt + 1 < nKT);
    uint4 vn0, vn1;
    if (more) {  // prefetch next tile: in flight across this iter's compute
      #pragma unroll
      for (int j = 0; j < 2; ++j) {
        int r = wave * 16 + j * 8;
        GLD16(&Kb[(long)((kt + 1) * 64 + r + rA) * N3C + cxor * 8],
              &Ks[buf ^ 1][r * 64]);
      }
      vn0 = *(const uint4*)&Vb[(long)rv * T_ + (kt + 1) * 64 + c16 * 8];
      vn1 = *(const uint4*)&Vb[(long)(rv + 32) * T_ + (kt + 1) * 64 + c16 * 8];
    }

    // S^T = K . Q^T  (A = K rows, B = Q rows)
    f32x4 St[4] = {};
    #pragma unroll
    for (int kk = 0; kk < 2; ++kk) {
      bf16x8 qf = kk ? bq1 : bq0;
      #pragma unroll
      for (int mt = 0; mt < 4; ++mt) {
        int r = mt * 16 + l15;
        int c = (kk * 4 + quad) ^ (l15 & 7);
        bf16x8 kf = *(const bf16x8*)&Ks[buf][r * 64 + c * 8];
        St[mt] = __builtin_amdgcn_mfma_f32_16x16x32_bf16(kf, qf, St[mt], 0, 0, 0);
      }
    }

    if (kt == qt) {  // causal mask on diagonal tile: k_local > q_local
      #pragma unroll
      for (int mt = 0; mt < 4; ++mt)
        #pragma unroll
        for (int r = 0; r < 4; ++r)
          if (mt * 16 + quad * 4 + r > wave * 16 + l15)
            St[mt][r] = -__builtin_inff();
    }

    // online softmax over k (per-lane 16 values + 2-stage cross-quad reduce)
    float mx = St[0][0];
    #pragma unroll
    for (int mt = 0; mt < 4; ++mt)
      #pragma unroll
      for (int r = 0; r < 4; ++r) mx = fmaxf(mx, St[mt][r]);
    mx = fmaxf(mx, __shfl_xor(mx, 16));
    mx = fmaxf(mx, __shfl_xor(mx, 32));
    float msn = fmaxf(ms, mx * cs);
    float al = EXP2F(ms - msn);
    ms = msn;

    float rs = 0.f;
    f16x4 pf[4];
    #pragma unroll
    for (int mt = 0; mt < 4; ++mt) {
      float p0 = EXP2F(__builtin_fmaf(St[mt][0], cs, -ms));
      float p1 = EXP2F(__builtin_fmaf(St[mt][1], cs, -ms));
      float p2 = EXP2F(__builtin_fmaf(St[mt][2], cs, -ms));
      float p3 = EXP2F(__builtin_fmaf(St[mt][3], cs, -ms));
      rs += (p0 + p1) + (p2 + p3);
      f16x2 lo = __builtin_bit_cast(f16x2, __builtin_amdgcn_cvt_pkrtz(p0, p1));
      f16x2 hi = __builtin_bit_cast(f16x2, __builtin_amdgcn_cvt_pkrtz(p2, p3));
      pf[mt][0] = lo[0]; pf[mt][1] = lo[1]; pf[mt][2] = hi[0]; pf[mt][3] = hi[1];
    }
    rs += __shfl_xor(rs, 16);
    rs += __shfl_xor(rs, 32);
    li = li * al + rs;
    #pragma unroll
    for (int dt = 0; dt < 4; ++dt) o[dt] *= al;

    // O^T += V^T . P^T   (A = V^T frags from padded LDS, B = P^T regs)
    #pragma unroll
    for (int dt = 0; dt < 4; ++dt) {
      #pragma unroll
      for (int kc = 0; kc < 4; ++kc) {
        f16x4 vf = *(const f16x4*)&Vts[buf][(dt * 16 + l15) * 72 + kc * 16 + quad * 4];
        o[dt] = __builtin_amdgcn_mfma_f32_16x16x16f16(vf, pf[kc], o[dt], 0, 0, 0);
      }
    }

    if (more) {  // commit V prefetch (load has been in flight all compute)
      *(uint4*)&Vts[buf ^ 1][rv * 72 + c16 * 8] = vn0;
      *(uint4*)&Vts[buf ^ 1][(rv + 32) * 72 + c16 * 8] = vn1;
    }
    __syncthreads();
  }

  float inv = 1.f / li;
  #pragma unroll
  for (int dt = 0; dt < 4; ++dt) {
    ushort4 w;
    w.x = f2bf(o[dt][0] * inv);
    w.y = f2bf(o[dt][1] * inv);
    w.z = f2bf(o[dt][2] * inv);
    w.w = f2bf(o[dt][3] * inv);
    *(ushort4*)&yb[((long)b * T_ + qrow) * C_ + h * HD_ + dt * 16 + quad * 4] = w;
  }
}

extern "C" void kernel_launch(void* const* d_in, const int* in_sizes, int n_in,
                              void* d_out, int out_size, void* d_ws, size_t ws_size,
                              hipStream_t stream) {
  const float* x      = (const float*)d_in[0];
  const float* W_attn = (const float*)d_in[1];
  const float* b_attn = (const float*)d_in[2];
  const float* W_proj = (const float*)d_in[3];
  const float* b_proj = (const float*)d_in[4];
  float* out = (float*)d_out;

  char* ws = (char*)d_ws;
  u16* xb   = (u16*)(ws);                      // 8192*1024*2  = 16777216
  f16* vtb  = (f16*)(ws);                      // alias of xb (xb dead by then)
  u16* W1t  = (u16*)(ws + 16777216);           // 3072*1024*2  =  6291456
  u16* W2t  = (u16*)(ws + 23068672);           // 1024*1024*2  =  2097152
  u16* qkvb = (u16*)(ws + 25165824);           // 8192*3072*2  = 50331648
  u16* yb   = (u16*)(ws + 75497472);           // 8192*1024*2  = 16777216

  cvt_f32_to_bf16<<<dim3((M_ * C_ / 4 + 255) / 256), dim3(256), 0, stream>>>(
      x, xb, M_ * C_ / 4);
  transpose_cvt<<<dim3(N3C / 32, C_ / 32), dim3(32, 8), 0, stream>>>(
      W_attn, W1t, C_, N3C);
  transpose_cvt<<<dim3(C_ / 32, C_ / 32), dim3(32, 8), 0, stream>>>(
      W_proj, W2t, C_, C_);
  gemm_bt<1><<<dim3(M_ / 128, N3C / 128), dim3(256), 0, stream>>>(
      xb, W1t, b_attn, qkvb, N3C, C_);
  transpose_v<<<dim3(T_ / 64, B_ * H_), dim3(256), 0, stream>>>(qkvb, vtb);
  flash_attn<<<dim3(T_ / 64, B_ * H_), dim3(256), 0, stream>>>(qkvb, vtb, yb);
  gemm_bt<0><<<dim3(M_ / 128, C_ / 128), dim3(256), 0, stream>>>(
      yb, W2t, b_proj, out, C_, C_);
}